// Round 1
// baseline (15.761 us; speedup 1.0000x reference)
//
#include <hip/hip_runtime.h>
#include <hip/hip_bf16.h>

// out[i] = b + sum_{k=0..7} (w[k]/k!) * X[i]^k   — Horner, float4-vectorized.
// Memory-bound: 64 MiB total traffic at N=8388608.

__global__ __launch_bounds__(256) void PolyModel_poly_kernel(
    const float* __restrict__ X,
    const float* __restrict__ w,
    const float* __restrict__ b,
    float* __restrict__ out,
    int n4)   // number of float4 elements
{
    // Uniform-address coefficient loads (L1-broadcast). Fold 1/k! and bias.
    const float c0 = w[0] + b[0];
    const float c1 = w[1];
    const float c2 = w[2] * 0.5f;
    const float c3 = w[3] * (1.0f / 6.0f);
    const float c4 = w[4] * (1.0f / 24.0f);
    const float c5 = w[5] * (1.0f / 120.0f);
    const float c6 = w[6] * (1.0f / 720.0f);
    const float c7 = w[7] * (1.0f / 5040.0f);

    const int stride = gridDim.x * blockDim.x;
    for (int i = blockIdx.x * blockDim.x + threadIdx.x; i < n4; i += stride) {
        float4 x = reinterpret_cast<const float4*>(X)[i];
        float4 r;
        r.x = fmaf(fmaf(fmaf(fmaf(fmaf(fmaf(fmaf(c7, x.x, c6), x.x, c5), x.x, c4), x.x, c3), x.x, c2), x.x, c1), x.x, c0);
        r.y = fmaf(fmaf(fmaf(fmaf(fmaf(fmaf(fmaf(c7, x.y, c6), x.y, c5), x.y, c4), x.y, c3), x.y, c2), x.y, c1), x.y, c0);
        r.z = fmaf(fmaf(fmaf(fmaf(fmaf(fmaf(fmaf(c7, x.z, c6), x.z, c5), x.z, c4), x.z, c3), x.z, c2), x.z, c1), x.z, c0);
        r.w = fmaf(fmaf(fmaf(fmaf(fmaf(fmaf(fmaf(c7, x.w, c6), x.w, c5), x.w, c4), x.w, c3), x.w, c2), x.w, c1), x.w, c0);
        reinterpret_cast<float4*>(out)[i] = r;
    }
}

extern "C" void kernel_launch(void* const* d_in, const int* in_sizes, int n_in,
                              void* d_out, int out_size, void* d_ws, size_t ws_size,
                              hipStream_t stream) {
    const float* X = (const float*)d_in[0];
    const float* w = (const float*)d_in[1];
    const float* b = (const float*)d_in[2];
    float* out = (float*)d_out;

    const int n = in_sizes[0];        // 8388608, divisible by 4
    const int n4 = n / 4;             // 2097152 float4s

    const int block = 256;
    int grid = (n4 + block - 1) / block;
    if (grid > 2048) grid = 2048;     // grid-stride the rest

    PolyModel_poly_kernel<<<grid, block, 0, stream>>>(X, w, b, out, n4);
}